// Round 14
// baseline (566.736 us; speedup 1.0000x reference)
//
#include <hip/hip_runtime.h>

#define N_NODES 50000
#define N_EDGES 800000
#define N_GRAPHS 512
#define IN_C 128
#define HID 256
#define OUT_C 16

typedef __attribute__((ext_vector_type(8))) short short8;
typedef __attribute__((ext_vector_type(4))) float f32x4;

__device__ __forceinline__ float bf2f(unsigned short u) {
    return __uint_as_float(((unsigned int)u) << 16);
}
__device__ __forceinline__ unsigned short f2bf(float f) {
    unsigned int u = __float_as_uint(f);
    u += 0x7fff + ((u >> 16) & 1);   // RNE
    return (unsigned short)(u >> 16);
}

// Planar layout: features stored as [C/32 planes][N_NODES][32 cols] bf16.
// Each plane is 50000*64B = 3.2 MB (contiguous) -> fits one XCD's 4 MB L2.
#define PLANE_ELEMS ((long)N_NODES * 32)

// ===========================================================================
// Prep (single dispatch): x -> bf16 PLANAR, zero deg, zero sums.
// ===========================================================================
struct PrepArgs {
    const float* x;
    ushort* xbf;            // planar [4][N][32]
    int* deg;
    float* sums;
};

__global__ __launch_bounds__(256) void prep_kernel(PrepArgs a) {
    const int X4    = N_NODES * IN_C / 4;
    const int D4    = N_NODES / 4;
    const int DBASE = X4;
    const int SBASE = DBASE + D4;
    const int S4    = N_GRAPHS * HID / 4;
    const long total = (long)SBASE + S4;

    long stride = (long)gridDim.x * blockDim.x;
    for (long i = (long)blockIdx.x * blockDim.x + threadIdx.x; i < total; i += stride) {
        if (i < X4) {
            float4 v = ((const float4*)a.x)[i];
            ushort4 o;
            o.x = f2bf(v.x); o.y = f2bf(v.y); o.z = f2bf(v.z); o.w = f2bf(v.w);
            long e = i * 4;
            int node = (int)(e >> 7);         // /128
            int col  = (int)(e & 127);
            long off = (long)(col >> 5) * PLANE_ELEMS + (long)node * 32 + (col & 31);
            *(ushort4*)(a.xbf + off) = o;
        } else if (i < SBASE) {
            ((int4*)a.deg)[i - DBASE] = make_int4(0, 0, 0, 0);
        } else {
            ((float4*)a.sums)[i - SBASE] = make_float4(0.f, 0.f, 0.f, 0.f);
        }
    }
}

// ===========================================================================
// Weight transpose via 32x32 LDS tiles: coalesced reads AND writes.
// ===========================================================================
struct TransArgs {
    const float* w[6];
    ushort* wt[6];
};

__global__ __launch_bounds__(256) void transpose_weights(TransArgs a) {
    __shared__ int tile[32][33];
    int bt = blockIdx.x;
    int wi, K, rel;
    if (bt < 32) { wi = 0; K = 128; rel = bt; }
    else { wi = 1 + (bt - 32) / 64; K = 256; rel = (bt - 32) % 64; }
    int k0 = (rel >> 3) * 32;
    int n0 = (rel & 7) * 32;

    const float* w = a.w[wi];
    ushort* wt = a.wt[wi];

    int t = threadIdx.x;
    int tn = t & 31, tk4 = t >> 5;       // read: coalesced over n
    #pragma unroll
    for (int r = 0; r < 4; ++r) {
        int row = tk4 + r * 8;           // k-offset within tile
        tile[row][tn] = f2bf(w[(long)(k0 + row) * HID + n0 + tn]);
    }
    __syncthreads();
    int tk2 = t & 31, tn4 = t >> 5;      // write: coalesced over k
    #pragma unroll
    for (int r = 0; r < 4; ++r) {
        int n2 = tn4 + r * 8;
        wt[(long)(n0 + n2) * K + k0 + tk2] = (ushort)tile[tk2][n2];
    }
}

// ===========================================================================
// CSR build: deg+rank+pack in one atomic pass -> scan -> XCD-sharded
// atomic-free scatter. pack = (dst<<16)|src; rank is ushort.
// ===========================================================================
__global__ void deg_rank_kernel(const int* __restrict__ src, const int* __restrict__ dst,
                                int* __restrict__ deg, ushort* __restrict__ rank16,
                                uint* __restrict__ pack) {
    int e = blockIdx.x * blockDim.x + threadIdx.x;
    if (e < N_EDGES) {
        int d = dst[e];
        rank16[e] = (ushort)atomicAdd(&deg[d], 1);
        pack[e] = ((uint)d << 16) | (uint)src[e];
    }
}

__global__ __launch_bounds__(256) void scan_block(const int* __restrict__ deg,
                                                  int* __restrict__ partial,
                                                  int* __restrict__ blockSums) {
    __shared__ int s[256];
    int t = threadIdx.x;
    int i = blockIdx.x * 256 + t;
    int v = (i < N_NODES) ? deg[i] : 0;
    s[t] = v;
    __syncthreads();
    #pragma unroll
    for (int off = 1; off < 256; off <<= 1) {
        int add = (t >= off) ? s[t - off] : 0;
        __syncthreads();
        s[t] += add;
        __syncthreads();
    }
    if (i < N_NODES) partial[i] = s[t] - v;
    if (t == 255) blockSums[blockIdx.x] = s[255];
}

__global__ __launch_bounds__(256) void add_offsets_fused(
    const int* __restrict__ partial, const int* __restrict__ blockSums,
    int* __restrict__ rowptr, int nb) {
    __shared__ int s[256];
    __shared__ int myOff;
    int t = threadIdx.x;
    int v = (t < nb) ? blockSums[t] : 0;
    s[t] = v;
    __syncthreads();
    #pragma unroll
    for (int off = 1; off < 256; off <<= 1) {
        int add = (t >= off) ? s[t - off] : 0;
        __syncthreads();
        s[t] += add;
        __syncthreads();
    }
    if (t == blockIdx.x) myOff = s[t] - v;
    __syncthreads();
    int i = blockIdx.x * 256 + t;
    if (i < N_NODES) rowptr[i] = partial[i] + myOff;
    if (i == 0) rowptr[N_NODES] = N_EDGES;
}

#define NSHARD 8
#define SHARD_SZ ((N_NODES + NSHARD - 1) / NSHARD)   // 6250
#define EDGES_PER_BLK 2048

__global__ __launch_bounds__(256) void scatter_edges_sharded(
    const uint* __restrict__ pack, const ushort* __restrict__ rank16,
    const int* __restrict__ rowptr, ushort* __restrict__ srcSorted) {
    int b = blockIdx.x;
    int shard = b & 7;
    int chunk = b >> 3;
    int lo = shard * SHARD_SZ;
    int hi = lo + SHARD_SZ;
    int base = chunk * EDGES_PER_BLK + threadIdx.x;
    #pragma unroll
    for (int u = 0; u < EDGES_PER_BLK / 256; ++u) {
        int e = base + u * 256;
        if (e < N_EDGES) {
            uint pk = pack[e];
            int d = (int)(pk >> 16);
            if (d >= lo && d < hi)
                srcSorted[rowptr[d] + rank16[e]] = (ushort)(pk & 0xFFFFu);
        }
    }
}

// ===========================================================================
// Aggregation: planar-in / row-major-out, LDS-staged edge indices (R13).
// ===========================================================================
template <int C>
__global__ __launch_bounds__(256) void gin_aggregate_planar(
    const ushort* __restrict__ hp,     // planar [C/32][N][32]
    const int* __restrict__ rowptr,
    const ushort* __restrict__ srcIdx,
    ushort* __restrict__ out)          // row-major [N][C]
{
    constexpr int NC  = C / 32;        // 4 (C=128) or 8 (C=256)
    constexpr int PER = 8 / NC;        // XCDs per plane (2 or 1)

    __shared__ ushort sIdx[8192];

    int b  = blockIdx.x;
    int x8 = b & 7;                    // presumed XCD id (round-robin)
    int chunk   = x8 / PER;
    int nodeblk = (b >> 3) * PER + (x8 & (PER - 1));

    int n0 = nodeblk * 64;
    int nEnd = n0 + 64; if (nEnd > N_NODES) nEnd = N_NODES;
    int rbeg = rowptr[n0];
    int rend = rowptr[nEnd];
    int cnt  = rend - rbeg;
    bool useLds = (cnt <= 8192);
    if (useLds) {
        for (int i = threadIdx.x; i < cnt; i += 256)
            sIdx[i] = srcIdx[rbeg + i];
    }
    __syncthreads();

    int lane = threadIdx.x & 63;
    int wave = threadIdx.x >> 6;
    int grp  = lane >> 2;              // 0..15: node within wave
    int l    = lane & 3;               // 4 lanes x 8 bf16 = 32 cols
    int node = n0 + wave * 16 + grp;
    if (node >= N_NODES) return;

    const ushort* plane = hp + (long)chunk * PLANE_ELEMS + l * 8;

    float acc[8];
    {
        short8 sv = *(const short8*)(plane + (long)node * 32);
        #pragma unroll
        for (int v = 0; v < 8; ++v) acc[v] = bf2f((unsigned short)sv[v]);
    }

    int beg = rowptr[node], end = rowptr[node + 1];

    auto gather = [&](auto idxAt) {
        int k = beg;
        for (; k + 8 <= end; k += 8) {
            int si[8];
            #pragma unroll
            for (int u = 0; u < 8; ++u) si[u] = idxAt(k + u);
            short8 r[8];
            #pragma unroll
            for (int u = 0; u < 8; ++u) r[u] = *(const short8*)(plane + (long)si[u] * 32);
            #pragma unroll
            for (int u = 0; u < 8; ++u)
                #pragma unroll
                for (int v = 0; v < 8; ++v) acc[v] += bf2f((unsigned short)r[u][v]);
        }
        for (; k + 2 <= end; k += 2) {
            int si0 = idxAt(k), si1 = idxAt(k + 1);
            short8 r0 = *(const short8*)(plane + (long)si0 * 32);
            short8 r1 = *(const short8*)(plane + (long)si1 * 32);
            #pragma unroll
            for (int v = 0; v < 8; ++v) acc[v] += bf2f((unsigned short)r0[v]);
            #pragma unroll
            for (int v = 0; v < 8; ++v) acc[v] += bf2f((unsigned short)r1[v]);
        }
        if (k < end) {
            short8 r = *(const short8*)(plane + (long)idxAt(k) * 32);
            #pragma unroll
            for (int v = 0; v < 8; ++v) acc[v] += bf2f((unsigned short)r[v]);
        }
    };

    if (useLds) gather([&](int k) { return (int)sIdx[k - rbeg]; });
    else        gather([&](int k) { return (int)srcIdx[k]; });

    short8 o;
    #pragma unroll
    for (int v = 0; v < 8; ++v) o[v] = (short)f2bf(acc[v]);
    __builtin_nontemporal_store(o, (short8*)(out + (long)node * C + chunk * 32 + l * 8));
}

// ===========================================================================
// PERSISTENT fused 2-layer MLP, v3: 2 blocks/CU co-residency.
// NPERS=512 (was 256): a second resident block runs its MFMA phases inside
// the first block's A-read / barrier-drain stalls (R13 profile: 15us/tile
// vs 0.6us compute floor, all pipes <11% -> phase-latency bound with no
// overlap partner). __launch_bounds__(512,4) pins VGPR cap at 128 (the
// measured use) so 16 waves/CU genuinely fit; LDS 2x64KB=128KB <= 160KB.
// ===========================================================================
template <int K1, bool FUSE_POOL>
__global__ __launch_bounds__(512, 4) void gin_mlp_persist(
    const ushort* __restrict__ A,
    const ushort* __restrict__ w1t,
    const float* __restrict__ b1,
    const ushort* __restrict__ w2t,
    const float* __restrict__ b2,
    ushort* __restrict__ out,          // planar [8][N][32]
    const int* __restrict__ batch,
    float* __restrict__ sums,
    int M, int nTiles, int nPers)
{
    constexpr int NCH1 = K1 / 8;        // 16 or 32
    constexpr int NSLOT1 = 64 * NCH1;   // 1024 or 2048
    constexpr int NS1 = K1 / 32;        // 4 or 8
    constexpr int PFN = NSLOT1 / 512;   // 2 or 4 short8 per thread per stage

    __shared__ short LsA[NSLOT1 * 8];   // 16 KB (K=128) / 32 KB (K=256)
    __shared__ short LsH[2048 * 8];     // 32 KB

    int t = threadIdx.x;
    int lane = t & 63;
    int wv = t >> 6;                    // 0..7
    int quad = lane >> 4;
    int l15 = lane & 15;
    int swz = l15 & 7;
    int col0 = wv * 32;

    short8 w1r[NS1 * 2];
    #pragma unroll
    for (int s = 0; s < NS1; ++s)
        #pragma unroll
        for (int j = 0; j < 2; ++j)
            w1r[s * 2 + j] = *(const short8*)(w1t + (long)(col0 + j * 16 + l15) * K1 + s * 32 + quad * 8);
    short8 w2r[16];
    #pragma unroll
    for (int s = 0; s < 8; ++s)
        #pragma unroll
        for (int j = 0; j < 2; ++j)
            w2r[s * 2 + j] = *(const short8*)(w2t + (long)(col0 + j * 16 + l15) * 256 + s * 32 + quad * 8);
    #pragma unroll
    for (int i = 0; i < NS1 * 2; ++i) asm volatile("" : "+v"(w1r[i]));
    #pragma unroll
    for (int i = 0; i < 16; ++i) asm volatile("" : "+v"(w2r[i]));

    float bv1[2], bv2[2];
    #pragma unroll
    for (int j = 0; j < 2; ++j) {
        bv1[j] = b1[col0 + j * 16 + l15];
        bv2[j] = b2[col0 + j * 16 + l15];
    }

    int prow[PFN], pkcB[PFN];
    #pragma unroll
    for (int c = 0; c < PFN; ++c) {
        int s = c * 512 + t;
        prow[c] = s / NCH1;
        int kcs = s & (NCH1 - 1);
        pkcB[c] = (kcs ^ (prow[c] & 7)) * 8;
    }

    int t0 = (int)(((long)blockIdx.x * nTiles) / nPers);
    int t1 = (int)(((long)(blockIdx.x + 1) * nTiles) / nPers);
    if (t0 >= t1) return;

    const f32x4 zero = {0.f, 0.f, 0.f, 0.f};

    short8 pf[PFN];
    {
        int row0 = t0 * 64;
        #pragma unroll
        for (int c = 0; c < PFN; ++c) {
            int grow = row0 + prow[c];
            if (grow >= M) grow = M - 1;
            pf[c] = *(const short8*)(A + (long)grow * K1 + pkcB[c]);
        }
    }

    for (int ti = t0; ti < t1; ++ti) {
        int row0 = ti * 64;

        #pragma unroll
        for (int c = 0; c < PFN; ++c)
            *(short8*)&LsA[(c * 512 + t) * 8] = pf[c];
        if (ti + 1 < t1) {
            int nrow0 = (ti + 1) * 64;
            #pragma unroll
            for (int c = 0; c < PFN; ++c) {
                int grow = nrow0 + prow[c];
                if (grow >= M) grow = M - 1;
                pf[c] = *(const short8*)(A + (long)grow * K1 + pkcB[c]);
            }
        }
        __syncthreads();                       // B1

        f32x4 acc[4][2];
        #pragma unroll
        for (int i = 0; i < 4; ++i)
            #pragma unroll
            for (int j = 0; j < 2; ++j) acc[i][j] = zero;

        #pragma unroll
        for (int s = 0; s < NS1; ++s) {
            #pragma unroll
            for (int i = 0; i < 4; ++i) {
                int row = i * 16 + l15;
                int slot = row * NCH1 + ((s * 4 + quad) ^ swz);
                short8 a = *(const short8*)&LsA[slot * 8];
                acc[i][0] = __builtin_amdgcn_mfma_f32_16x16x32_bf16(a, w1r[s * 2 + 0], acc[i][0], 0, 0, 0);
                acc[i][1] = __builtin_amdgcn_mfma_f32_16x16x32_bf16(a, w1r[s * 2 + 1], acc[i][1], 0, 0, 0);
            }
        }
        __syncthreads();                       // B2

        #pragma unroll
        for (int i = 0; i < 4; ++i)
            #pragma unroll
            for (int j = 0; j < 2; ++j) {
                int col = col0 + j * 16 + l15;
                int kc2 = col >> 3, sub = col & 7;
                #pragma unroll
                for (int r = 0; r < 4; ++r) {
                    int row = i * 16 + quad * 4 + r;
                    int slot = row * 32 + (kc2 ^ (row & 7));
                    float o = fmaxf(acc[i][j][r] + bv1[j], 0.f);
                    LsH[slot * 8 + sub] = (short)f2bf(o);
                }
            }
        __syncthreads();                       // B3

        #pragma unroll
        for (int i = 0; i < 4; ++i)
            #pragma unroll
            for (int j = 0; j < 2; ++j) acc[i][j] = zero;

        #pragma unroll
        for (int s = 0; s < 8; ++s) {
            #pragma unroll
            for (int i = 0; i < 4; ++i) {
                int row = i * 16 + l15;
                int slot = row * 32 + ((s * 4 + quad) ^ swz);
                short8 a = *(const short8*)&LsH[slot * 8];
                acc[i][0] = __builtin_amdgcn_mfma_f32_16x16x32_bf16(a, w2r[s * 2 + 0], acc[i][0], 0, 0, 0);
                acc[i][1] = __builtin_amdgcn_mfma_f32_16x16x32_bf16(a, w2r[s * 2 + 1], acc[i][1], 0, 0, 0);
            }
        }

        if constexpr (!FUSE_POOL) {
            #pragma unroll
            for (int i = 0; i < 4; ++i)
                #pragma unroll
                for (int r = 0; r < 4; ++r) {
                    int grow = row0 + i * 16 + quad * 4 + r;
                    if (grow >= M) continue;
                    #pragma unroll
                    for (int j = 0; j < 2; ++j) {
                        int col = col0 + j * 16 + l15;
                        float o = fmaxf(acc[i][j][r] + bv2[j], 0.f);
                        out[(long)(col >> 5) * PLANE_ELEMS + (long)grow * 32 + (col & 31)] = f2bf(o);
                    }
                }
        } else {
            float pacc[2];
            #pragma unroll
            for (int j = 0; j < 2; ++j) pacc[j] = 0.f;
            int cur = -1;
            #pragma unroll
            for (int i = 0; i < 4; ++i) {
                #pragma unroll
                for (int r = 0; r < 4; ++r) {
                    int row = row0 + i * 16 + quad * 4 + r;
                    if (row >= M) continue;
                    int g = batch[row];
                    if (g != cur) {
                        if (cur >= 0) {
                            #pragma unroll
                            for (int j = 0; j < 2; ++j)
                                atomicAdd(&sums[(long)cur * 256 + col0 + j * 16 + l15], pacc[j]);
                        }
                        cur = g;
                        #pragma unroll
                        for (int j = 0; j < 2; ++j) pacc[j] = 0.f;
                    }
                    #pragma unroll
                    for (int j = 0; j < 2; ++j)
                        pacc[j] += fmaxf(acc[i][j][r] + bv2[j], 0.f);
                }
            }
            if (cur >= 0) {
                #pragma unroll
                for (int j = 0; j < 2; ++j)
                    atomicAdd(&sums[(long)cur * 256 + col0 + j * 16 + l15], pacc[j]);
            }
        }
    }
}

// ===========================================================================
// Head MLP (fp32): one block per graph; count via binary search on batch.
// ===========================================================================
__global__ __launch_bounds__(256) void final_mlp_kernel(
    const float* __restrict__ sums, const int* __restrict__ batch,
    const float* __restrict__ w1, const float* __restrict__ b1,
    const float* __restrict__ w2, const float* __restrict__ b2,
    float* __restrict__ out) {
    __shared__ float row[HID];
    __shared__ float hid[HID];
    __shared__ int cntS;
    int g = blockIdx.x;
    int t = threadIdx.x;
    if (t == 0) {
        int lo = 0, hi = N_NODES;
        while (lo < hi) { int m = (lo + hi) >> 1; if (batch[m] < g) lo = m + 1; else hi = m; }
        int lo2 = lo, hi2 = N_NODES;
        while (lo2 < hi2) { int m = (lo2 + hi2) >> 1; if (batch[m] < g + 1) lo2 = m + 1; else hi2 = m; }
        cntS = lo2 - lo;
    }
    __syncthreads();
    float cnt = fmaxf((float)cntS, 1.0f);
    row[t] = sums[(long)g * HID + t] / cnt;
    __syncthreads();
    float acc = b1[t];
    for (int k = 0; k < HID; ++k) acc += row[k] * w1[k * HID + t];
    hid[t] = fmaxf(acc, 0.f);
    __syncthreads();
    if (t < OUT_C) {
        float o = b2[t];
        for (int k = 0; k < HID; ++k) o += hid[k] * w2[k * OUT_C + t];
        out[(long)g * OUT_C + t] = o;
    }
}

// ---------------------------------------------------------------------------
extern "C" void kernel_launch(void* const* d_in, const int* in_sizes, int n_in,
                              void* d_out, int out_size, void* d_ws, size_t ws_size,
                              hipStream_t stream) {
    const float* x     = (const float*)d_in[0];
    const int*   ei    = (const int*)d_in[1];
    const int*   batch = (const int*)d_in[2];
    const int*   src   = ei;
    const int*   dst   = ei + N_EDGES;

    const float* c_w1[3] = { (const float*)d_in[3],  (const float*)d_in[7],  (const float*)d_in[11] };
    const float* c_b1[3] = { (const float*)d_in[4],  (const float*)d_in[8],  (const float*)d_in[12] };
    const float* c_w2[3] = { (const float*)d_in[5],  (const float*)d_in[9],  (const float*)d_in[13] };
    const float* c_b2[3] = { (const float*)d_in[6],  (const float*)d_in[10], (const float*)d_in[14] };
    const float* out_w1 = (const float*)d_in[15];
    const float* out_b1 = (const float*)d_in[16];
    const float* out_w2 = (const float*)d_in[17];
    const float* out_b2 = (const float*)d_in[18];

    // ---- Workspace layout (16B aligned) ----
    char* p = (char*)d_ws;
    auto alloc = [&](size_t bytes) {
        char* r = p;
        p += (bytes + 15) & ~(size_t)15;
        return r;
    };
    ushort* xbf  = (ushort*)alloc((size_t)N_NODES * IN_C * 2);   // planar [4][N][32]
    ushort* bufA = (ushort*)alloc((size_t)N_NODES * HID * 2);    // planar [8][N][32]
    ushort* bufB = (ushort*)alloc((size_t)N_NODES * HID * 2);    // row-major agg output
    ushort* wt[6];
    wt[0] = (ushort*)alloc((size_t)IN_C * HID * 2);
    for (int i = 1; i < 6; ++i) wt[i] = (ushort*)alloc((size_t)HID * HID * 2);
    float* sums   = (float*)alloc((size_t)N_GRAPHS * HID * 4);
    int* deg       = (int*)alloc((size_t)N_NODES * 4);
    int* rowptr    = (int*)alloc((size_t)(N_NODES + 1) * 4);
    int* blockSums = (int*)alloc(256 * 4);
    ushort* rank16 = (ushort*)alloc((size_t)N_EDGES * 2);
    uint* pack     = (uint*)alloc((size_t)N_EDGES * 4);
    ushort* srcSorted = (ushort*)alloc((size_t)N_EDGES * 2);     // USHORT indices

    const int nb = (N_NODES + 255) / 256;

    // ---- Prep: casts + zeroing ----
    {
        PrepArgs a;
        a.x = x;
        a.xbf = xbf;
        a.deg = deg;
        a.sums = sums;
        prep_kernel<<<2048, 256, 0, stream>>>(a);
    }
    // ---- Coalesced weight transposes (352 tiles of 32x32) ----
    {
        TransArgs ta;
        ta.w[0] = c_w1[0]; ta.w[1] = c_w2[0];
        ta.w[2] = c_w1[1]; ta.w[3] = c_w2[1];
        ta.w[4] = c_w1[2]; ta.w[5] = c_w2[2];
        for (int i = 0; i < 6; ++i) ta.wt[i] = wt[i];
        transpose_weights<<<352, 256, 0, stream>>>(ta);
    }

    // ---- Build CSR by dst: deg+rank+pack -> scan -> sharded scatter ----
    deg_rank_kernel<<<(N_EDGES + 255) / 256, 256, 0, stream>>>(src, dst, deg, rank16, pack);
    scan_block<<<nb, 256, 0, stream>>>(deg, rowptr, blockSums);
    add_offsets_fused<<<nb, 256, 0, stream>>>(rowptr, blockSums, rowptr, nb);
    {
        const int chunks = (N_EDGES + EDGES_PER_BLK - 1) / EDGES_PER_BLK;  // 391
        scatter_edges_sharded<<<chunks * NSHARD, 256, 0, stream>>>(pack, rank16, rowptr, srcSorted);
    }

    const int nodeBlks = (N_NODES + 63) / 64;        // 782 (even, needed for PER=2)
    const int aggX128  = nodeBlks * (IN_C / 32);     // 3128
    const int aggX256  = nodeBlks * (HID / 32);      // 6256
    const int NPERS    = 512;                        // persistent MLP grid (2/CU)

    // ---- Layer 0 (C_in = 128) ----
    gin_aggregate_planar<IN_C><<<aggX128, 256, 0, stream>>>(xbf, rowptr, srcSorted, bufB);
    gin_mlp_persist<IN_C, false><<<NPERS, 512, 0, stream>>>(bufB, wt[0], c_b1[0], wt[1], c_b2[0],
                                                            bufA, batch, sums, N_NODES, nodeBlks, NPERS);

    // ---- Layer 1 (C = 256) ----
    gin_aggregate_planar<HID><<<aggX256, 256, 0, stream>>>(bufA, rowptr, srcSorted, bufB);
    gin_mlp_persist<HID, false><<<NPERS, 512, 0, stream>>>(bufB, wt[2], c_b1[1], wt[3], c_b2[1],
                                                           bufA, batch, sums, N_NODES, nodeBlks, NPERS);

    // ---- Layer 2 (C = 256) with fused global mean-pool accumulation ----
    gin_aggregate_planar<HID><<<aggX256, 256, 0, stream>>>(bufA, rowptr, srcSorted, bufB);
    gin_mlp_persist<HID, true><<<NPERS, 512, 0, stream>>>(bufB, wt[4], c_b1[2], wt[5], c_b2[2],
                                                          bufA, batch, sums, N_NODES, nodeBlks, NPERS);

    // ---- Head MLP ----
    final_mlp_kernel<<<N_GRAPHS, 256, 0, stream>>>(sums, batch, out_w1, out_b1,
                                                   out_w2, out_b2, (float*)d_out);
}

// Round 15
// 373.073 us; speedup vs baseline: 1.5191x; 1.5191x over previous
//
#include <hip/hip_runtime.h>

#define N_NODES 50000
#define N_EDGES 800000
#define N_GRAPHS 512
#define IN_C 128
#define HID 256
#define OUT_C 16

typedef __attribute__((ext_vector_type(8))) short short8;
typedef __attribute__((ext_vector_type(4))) float f32x4;

__device__ __forceinline__ float bf2f(unsigned short u) {
    return __uint_as_float(((unsigned int)u) << 16);
}
__device__ __forceinline__ unsigned short f2bf(float f) {
    unsigned int u = __float_as_uint(f);
    u += 0x7fff + ((u >> 16) & 1);   // RNE
    return (unsigned short)(u >> 16);
}

// Planar layout: features stored as [C/32 planes][N_NODES][32 cols] bf16.
// Each plane is 50000*64B = 3.2 MB (contiguous) -> fits one XCD's 4 MB L2.
#define PLANE_ELEMS ((long)N_NODES * 32)

// ===========================================================================
// Prep (single dispatch): x -> bf16 PLANAR, zero deg, zero sums.
// ===========================================================================
struct PrepArgs {
    const float* x;
    ushort* xbf;            // planar [4][N][32]
    int* deg;
    float* sums;
};

__global__ __launch_bounds__(256) void prep_kernel(PrepArgs a) {
    const int X4    = N_NODES * IN_C / 4;
    const int D4    = N_NODES / 4;
    const int DBASE = X4;
    const int SBASE = DBASE + D4;
    const int S4    = N_GRAPHS * HID / 4;
    const long total = (long)SBASE + S4;

    long stride = (long)gridDim.x * blockDim.x;
    for (long i = (long)blockIdx.x * blockDim.x + threadIdx.x; i < total; i += stride) {
        if (i < X4) {
            float4 v = ((const float4*)a.x)[i];
            ushort4 o;
            o.x = f2bf(v.x); o.y = f2bf(v.y); o.z = f2bf(v.z); o.w = f2bf(v.w);
            long e = i * 4;
            int node = (int)(e >> 7);         // /128
            int col  = (int)(e & 127);
            long off = (long)(col >> 5) * PLANE_ELEMS + (long)node * 32 + (col & 31);
            *(ushort4*)(a.xbf + off) = o;
        } else if (i < SBASE) {
            ((int4*)a.deg)[i - DBASE] = make_int4(0, 0, 0, 0);
        } else {
            ((float4*)a.sums)[i - SBASE] = make_float4(0.f, 0.f, 0.f, 0.f);
        }
    }
}

// ===========================================================================
// Weight transpose via 32x32 LDS tiles: coalesced reads AND writes.
// ===========================================================================
struct TransArgs {
    const float* w[6];
    ushort* wt[6];
};

__global__ __launch_bounds__(256) void transpose_weights(TransArgs a) {
    __shared__ int tile[32][33];
    int bt = blockIdx.x;
    int wi, K, rel;
    if (bt < 32) { wi = 0; K = 128; rel = bt; }
    else { wi = 1 + (bt - 32) / 64; K = 256; rel = (bt - 32) % 64; }
    int k0 = (rel >> 3) * 32;
    int n0 = (rel & 7) * 32;

    const float* w = a.w[wi];
    ushort* wt = a.wt[wi];

    int t = threadIdx.x;
    int tn = t & 31, tk4 = t >> 5;       // read: coalesced over n
    #pragma unroll
    for (int r = 0; r < 4; ++r) {
        int row = tk4 + r * 8;           // k-offset within tile
        tile[row][tn] = f2bf(w[(long)(k0 + row) * HID + n0 + tn]);
    }
    __syncthreads();
    int tk2 = t & 31, tn4 = t >> 5;      // write: coalesced over k
    #pragma unroll
    for (int r = 0; r < 4; ++r) {
        int n2 = tn4 + r * 8;
        wt[(long)(n0 + n2) * K + k0 + tk2] = (ushort)tile[tk2][n2];
    }
}

// ===========================================================================
// CSR build: deg+rank+pack in one atomic pass -> scan -> XCD-sharded
// atomic-free scatter. pack = (dst<<16)|src; rank is ushort.
// ===========================================================================
__global__ void deg_rank_kernel(const int* __restrict__ src, const int* __restrict__ dst,
                                int* __restrict__ deg, ushort* __restrict__ rank16,
                                uint* __restrict__ pack) {
    int e = blockIdx.x * blockDim.x + threadIdx.x;
    if (e < N_EDGES) {
        int d = dst[e];
        rank16[e] = (ushort)atomicAdd(&deg[d], 1);
        pack[e] = ((uint)d << 16) | (uint)src[e];
    }
}

__global__ __launch_bounds__(256) void scan_block(const int* __restrict__ deg,
                                                  int* __restrict__ partial,
                                                  int* __restrict__ blockSums) {
    __shared__ int s[256];
    int t = threadIdx.x;
    int i = blockIdx.x * 256 + t;
    int v = (i < N_NODES) ? deg[i] : 0;
    s[t] = v;
    __syncthreads();
    #pragma unroll
    for (int off = 1; off < 256; off <<= 1) {
        int add = (t >= off) ? s[t - off] : 0;
        __syncthreads();
        s[t] += add;
        __syncthreads();
    }
    if (i < N_NODES) partial[i] = s[t] - v;
    if (t == 255) blockSums[blockIdx.x] = s[255];
}

__global__ __launch_bounds__(256) void add_offsets_fused(
    const int* __restrict__ partial, const int* __restrict__ blockSums,
    int* __restrict__ rowptr, int nb) {
    __shared__ int s[256];
    __shared__ int myOff;
    int t = threadIdx.x;
    int v = (t < nb) ? blockSums[t] : 0;
    s[t] = v;
    __syncthreads();
    #pragma unroll
    for (int off = 1; off < 256; off <<= 1) {
        int add = (t >= off) ? s[t - off] : 0;
        __syncthreads();
        s[t] += add;
        __syncthreads();
    }
    if (t == blockIdx.x) myOff = s[t] - v;
    __syncthreads();
    int i = blockIdx.x * 256 + t;
    if (i < N_NODES) rowptr[i] = partial[i] + myOff;
    if (i == 0) rowptr[N_NODES] = N_EDGES;
}

#define NSHARD 8
#define SHARD_SZ ((N_NODES + NSHARD - 1) / NSHARD)   // 6250
#define EDGES_PER_BLK 2048

__global__ __launch_bounds__(256) void scatter_edges_sharded(
    const uint* __restrict__ pack, const ushort* __restrict__ rank16,
    const int* __restrict__ rowptr, ushort* __restrict__ srcSorted) {
    int b = blockIdx.x;
    int shard = b & 7;
    int chunk = b >> 3;
    int lo = shard * SHARD_SZ;
    int hi = lo + SHARD_SZ;
    int base = chunk * EDGES_PER_BLK + threadIdx.x;
    #pragma unroll
    for (int u = 0; u < EDGES_PER_BLK / 256; ++u) {
        int e = base + u * 256;
        if (e < N_EDGES) {
            uint pk = pack[e];
            int d = (int)(pk >> 16);
            if (d >= lo && d < hi)
                srcSorted[rowptr[d] + rank16[e]] = (ushort)(pk & 0xFFFFu);
        }
    }
}

// ===========================================================================
// Aggregation: planar-in / row-major-out, LDS-staged edge indices (R13).
// ===========================================================================
template <int C>
__global__ __launch_bounds__(256) void gin_aggregate_planar(
    const ushort* __restrict__ hp,     // planar [C/32][N][32]
    const int* __restrict__ rowptr,
    const ushort* __restrict__ srcIdx,
    ushort* __restrict__ out)          // row-major [N][C]
{
    constexpr int NC  = C / 32;        // 4 (C=128) or 8 (C=256)
    constexpr int PER = 8 / NC;        // XCDs per plane (2 or 1)

    __shared__ ushort sIdx[8192];

    int b  = blockIdx.x;
    int x8 = b & 7;                    // presumed XCD id (round-robin)
    int chunk   = x8 / PER;
    int nodeblk = (b >> 3) * PER + (x8 & (PER - 1));

    int n0 = nodeblk * 64;
    int nEnd = n0 + 64; if (nEnd > N_NODES) nEnd = N_NODES;
    int rbeg = rowptr[n0];
    int rend = rowptr[nEnd];
    int cnt  = rend - rbeg;
    bool useLds = (cnt <= 8192);
    if (useLds) {
        for (int i = threadIdx.x; i < cnt; i += 256)
            sIdx[i] = srcIdx[rbeg + i];
    }
    __syncthreads();

    int lane = threadIdx.x & 63;
    int wave = threadIdx.x >> 6;
    int grp  = lane >> 2;              // 0..15: node within wave
    int l    = lane & 3;               // 4 lanes x 8 bf16 = 32 cols
    int node = n0 + wave * 16 + grp;
    if (node >= N_NODES) return;

    const ushort* plane = hp + (long)chunk * PLANE_ELEMS + l * 8;

    float acc[8];
    {
        short8 sv = *(const short8*)(plane + (long)node * 32);
        #pragma unroll
        for (int v = 0; v < 8; ++v) acc[v] = bf2f((unsigned short)sv[v]);
    }

    int beg = rowptr[node], end = rowptr[node + 1];

    auto gather = [&](auto idxAt) {
        int k = beg;
        for (; k + 8 <= end; k += 8) {
            int si[8];
            #pragma unroll
            for (int u = 0; u < 8; ++u) si[u] = idxAt(k + u);
            short8 r[8];
            #pragma unroll
            for (int u = 0; u < 8; ++u) r[u] = *(const short8*)(plane + (long)si[u] * 32);
            #pragma unroll
            for (int u = 0; u < 8; ++u)
                #pragma unroll
                for (int v = 0; v < 8; ++v) acc[v] += bf2f((unsigned short)r[u][v]);
        }
        for (; k + 2 <= end; k += 2) {
            int si0 = idxAt(k), si1 = idxAt(k + 1);
            short8 r0 = *(const short8*)(plane + (long)si0 * 32);
            short8 r1 = *(const short8*)(plane + (long)si1 * 32);
            #pragma unroll
            for (int v = 0; v < 8; ++v) acc[v] += bf2f((unsigned short)r0[v]);
            #pragma unroll
            for (int v = 0; v < 8; ++v) acc[v] += bf2f((unsigned short)r1[v]);
        }
        if (k < end) {
            short8 r = *(const short8*)(plane + (long)idxAt(k) * 32);
            #pragma unroll
            for (int v = 0; v < 8; ++v) acc[v] += bf2f((unsigned short)r[v]);
        }
    };

    if (useLds) gather([&](int k) { return (int)sIdx[k - rbeg]; });
    else        gather([&](int k) { return (int)srcIdx[k]; });

    short8 o;
    #pragma unroll
    for (int v = 0; v < 8; ++v) o[v] = (short)f2bf(acc[v]);
    __builtin_nontemporal_store(o, (short8*)(out + (long)node * C + chunk * 32 + l * 8));
}

// ===========================================================================
// PERSISTENT fused 2-layer MLP (R13 form — FROZEN, final).
// launch_bounds(512,2): 256-VGPR cap funds pinned W1+W2 (128 VGPR) without
// spill. R14 proved 2-blocks/CU co-residency is unfundable: the (512,4)
// 128-VGPR cap forced the pinned weights to scratch (FETCH+WRITE ~290MB,
// dur 45.5 -> 114us). Within-block phase latency is this structure's floor.
// ===========================================================================
template <int K1, bool FUSE_POOL>
__global__ __launch_bounds__(512, 2) void gin_mlp_persist(
    const ushort* __restrict__ A,
    const ushort* __restrict__ w1t,
    const float* __restrict__ b1,
    const ushort* __restrict__ w2t,
    const float* __restrict__ b2,
    ushort* __restrict__ out,          // planar [8][N][32]
    const int* __restrict__ batch,
    float* __restrict__ sums,
    int M, int nTiles, int nPers)
{
    constexpr int NCH1 = K1 / 8;        // 16 or 32
    constexpr int NSLOT1 = 64 * NCH1;   // 1024 or 2048
    constexpr int NS1 = K1 / 32;        // 4 or 8
    constexpr int PFN = NSLOT1 / 512;   // 2 or 4 short8 per thread per stage

    __shared__ short LsA[NSLOT1 * 8];   // 16 KB (K=128) / 32 KB (K=256)
    __shared__ short LsH[2048 * 8];     // 32 KB

    int t = threadIdx.x;
    int lane = t & 63;
    int wv = t >> 6;                    // 0..7
    int quad = lane >> 4;
    int l15 = lane & 15;
    int swz = l15 & 7;
    int col0 = wv * 32;

    short8 w1r[NS1 * 2];
    #pragma unroll
    for (int s = 0; s < NS1; ++s)
        #pragma unroll
        for (int j = 0; j < 2; ++j)
            w1r[s * 2 + j] = *(const short8*)(w1t + (long)(col0 + j * 16 + l15) * K1 + s * 32 + quad * 8);
    short8 w2r[16];
    #pragma unroll
    for (int s = 0; s < 8; ++s)
        #pragma unroll
        for (int j = 0; j < 2; ++j)
            w2r[s * 2 + j] = *(const short8*)(w2t + (long)(col0 + j * 16 + l15) * 256 + s * 32 + quad * 8);
    #pragma unroll
    for (int i = 0; i < NS1 * 2; ++i) asm volatile("" : "+v"(w1r[i]));
    #pragma unroll
    for (int i = 0; i < 16; ++i) asm volatile("" : "+v"(w2r[i]));

    float bv1[2], bv2[2];
    #pragma unroll
    for (int j = 0; j < 2; ++j) {
        bv1[j] = b1[col0 + j * 16 + l15];
        bv2[j] = b2[col0 + j * 16 + l15];
    }

    int prow[PFN], pkcB[PFN];
    #pragma unroll
    for (int c = 0; c < PFN; ++c) {
        int s = c * 512 + t;
        prow[c] = s / NCH1;
        int kcs = s & (NCH1 - 1);
        pkcB[c] = (kcs ^ (prow[c] & 7)) * 8;
    }

    int t0 = (int)(((long)blockIdx.x * nTiles) / nPers);
    int t1 = (int)(((long)(blockIdx.x + 1) * nTiles) / nPers);
    if (t0 >= t1) return;

    const f32x4 zero = {0.f, 0.f, 0.f, 0.f};

    short8 pf[PFN];
    {
        int row0 = t0 * 64;
        #pragma unroll
        for (int c = 0; c < PFN; ++c) {
            int grow = row0 + prow[c];
            if (grow >= M) grow = M - 1;
            pf[c] = *(const short8*)(A + (long)grow * K1 + pkcB[c]);
        }
    }

    for (int ti = t0; ti < t1; ++ti) {
        int row0 = ti * 64;

        #pragma unroll
        for (int c = 0; c < PFN; ++c)
            *(short8*)&LsA[(c * 512 + t) * 8] = pf[c];
        if (ti + 1 < t1) {
            int nrow0 = (ti + 1) * 64;
            #pragma unroll
            for (int c = 0; c < PFN; ++c) {
                int grow = nrow0 + prow[c];
                if (grow >= M) grow = M - 1;
                pf[c] = *(const short8*)(A + (long)grow * K1 + pkcB[c]);
            }
        }
        __syncthreads();                       // B1

        f32x4 acc[4][2];
        #pragma unroll
        for (int i = 0; i < 4; ++i)
            #pragma unroll
            for (int j = 0; j < 2; ++j) acc[i][j] = zero;

        #pragma unroll
        for (int s = 0; s < NS1; ++s) {
            #pragma unroll
            for (int i = 0; i < 4; ++i) {
                int row = i * 16 + l15;
                int slot = row * NCH1 + ((s * 4 + quad) ^ swz);
                short8 a = *(const short8*)&LsA[slot * 8];
                acc[i][0] = __builtin_amdgcn_mfma_f32_16x16x32_bf16(a, w1r[s * 2 + 0], acc[i][0], 0, 0, 0);
                acc[i][1] = __builtin_amdgcn_mfma_f32_16x16x32_bf16(a, w1r[s * 2 + 1], acc[i][1], 0, 0, 0);
            }
        }
        __syncthreads();                       // B2

        #pragma unroll
        for (int i = 0; i < 4; ++i)
            #pragma unroll
            for (int j = 0; j < 2; ++j) {
                int col = col0 + j * 16 + l15;
                int kc2 = col >> 3, sub = col & 7;
                #pragma unroll
                for (int r = 0; r < 4; ++r) {
                    int row = i * 16 + quad * 4 + r;
                    int slot = row * 32 + (kc2 ^ (row & 7));
                    float o = fmaxf(acc[i][j][r] + bv1[j], 0.f);
                    LsH[slot * 8 + sub] = (short)f2bf(o);
                }
            }
        __syncthreads();                       // B3

        #pragma unroll
        for (int i = 0; i < 4; ++i)
            #pragma unroll
            for (int j = 0; j < 2; ++j) acc[i][j] = zero;

        #pragma unroll
        for (int s = 0; s < 8; ++s) {
            #pragma unroll
            for (int i = 0; i < 4; ++i) {
                int row = i * 16 + l15;
                int slot = row * 32 + ((s * 4 + quad) ^ swz);
                short8 a = *(const short8*)&LsH[slot * 8];
                acc[i][0] = __builtin_amdgcn_mfma_f32_16x16x32_bf16(a, w2r[s * 2 + 0], acc[i][0], 0, 0, 0);
                acc[i][1] = __builtin_amdgcn_mfma_f32_16x16x32_bf16(a, w2r[s * 2 + 1], acc[i][1], 0, 0, 0);
            }
        }

        if constexpr (!FUSE_POOL) {
            #pragma unroll
            for (int i = 0; i < 4; ++i)
                #pragma unroll
                for (int r = 0; r < 4; ++r) {
                    int grow = row0 + i * 16 + quad * 4 + r;
                    if (grow >= M) continue;
                    #pragma unroll
                    for (int j = 0; j < 2; ++j) {
                        int col = col0 + j * 16 + l15;
                        float o = fmaxf(acc[i][j][r] + bv2[j], 0.f);
                        out[(long)(col >> 5) * PLANE_ELEMS + (long)grow * 32 + (col & 31)] = f2bf(o);
                    }
                }
        } else {
            float pacc[2];
            #pragma unroll
            for (int j = 0; j < 2; ++j) pacc[j] = 0.f;
            int cur = -1;
            #pragma unroll
            for (int i = 0; i < 4; ++i) {
                #pragma unroll
                for (int r = 0; r < 4; ++r) {
                    int row = row0 + i * 16 + quad * 4 + r;
                    if (row >= M) continue;
                    int g = batch[row];
                    if (g != cur) {
                        if (cur >= 0) {
                            #pragma unroll
                            for (int j = 0; j < 2; ++j)
                                atomicAdd(&sums[(long)cur * 256 + col0 + j * 16 + l15], pacc[j]);
                        }
                        cur = g;
                        #pragma unroll
                        for (int j = 0; j < 2; ++j) pacc[j] = 0.f;
                    }
                    #pragma unroll
                    for (int j = 0; j < 2; ++j)
                        pacc[j] += fmaxf(acc[i][j][r] + bv2[j], 0.f);
                }
            }
            if (cur >= 0) {
                #pragma unroll
                for (int j = 0; j < 2; ++j)
                    atomicAdd(&sums[(long)cur * 256 + col0 + j * 16 + l15], pacc[j]);
            }
        }
    }
}

// ===========================================================================
// Head MLP (fp32): one block per graph; count via binary search on batch.
// ===========================================================================
__global__ __launch_bounds__(256) void final_mlp_kernel(
    const float* __restrict__ sums, const int* __restrict__ batch,
    const float* __restrict__ w1, const float* __restrict__ b1,
    const float* __restrict__ w2, const float* __restrict__ b2,
    float* __restrict__ out) {
    __shared__ float row[HID];
    __shared__ float hid[HID];
    __shared__ int cntS;
    int g = blockIdx.x;
    int t = threadIdx.x;
    if (t == 0) {
        int lo = 0, hi = N_NODES;
        while (lo < hi) { int m = (lo + hi) >> 1; if (batch[m] < g) lo = m + 1; else hi = m; }
        int lo2 = lo, hi2 = N_NODES;
        while (lo2 < hi2) { int m = (lo2 + hi2) >> 1; if (batch[m] < g + 1) lo2 = m + 1; else hi2 = m; }
        cntS = lo2 - lo;
    }
    __syncthreads();
    float cnt = fmaxf((float)cntS, 1.0f);
    row[t] = sums[(long)g * HID + t] / cnt;
    __syncthreads();
    float acc = b1[t];
    for (int k = 0; k < HID; ++k) acc += row[k] * w1[k * HID + t];
    hid[t] = fmaxf(acc, 0.f);
    __syncthreads();
    if (t < OUT_C) {
        float o = b2[t];
        for (int k = 0; k < HID; ++k) o += hid[k] * w2[k * OUT_C + t];
        out[(long)g * OUT_C + t] = o;
    }
}

// ---------------------------------------------------------------------------
extern "C" void kernel_launch(void* const* d_in, const int* in_sizes, int n_in,
                              void* d_out, int out_size, void* d_ws, size_t ws_size,
                              hipStream_t stream) {
    const float* x     = (const float*)d_in[0];
    const int*   ei    = (const int*)d_in[1];
    const int*   batch = (const int*)d_in[2];
    const int*   src   = ei;
    const int*   dst   = ei + N_EDGES;

    const float* c_w1[3] = { (const float*)d_in[3],  (const float*)d_in[7],  (const float*)d_in[11] };
    const float* c_b1[3] = { (const float*)d_in[4],  (const float*)d_in[8],  (const float*)d_in[12] };
    const float* c_w2[3] = { (const float*)d_in[5],  (const float*)d_in[9],  (const float*)d_in[13] };
    const float* c_b2[3] = { (const float*)d_in[6],  (const float*)d_in[10], (const float*)d_in[14] };
    const float* out_w1 = (const float*)d_in[15];
    const float* out_b1 = (const float*)d_in[16];
    const float* out_w2 = (const float*)d_in[17];
    const float* out_b2 = (const float*)d_in[18];

    // ---- Workspace layout (16B aligned) ----
    char* p = (char*)d_ws;
    auto alloc = [&](size_t bytes) {
        char* r = p;
        p += (bytes + 15) & ~(size_t)15;
        return r;
    };
    ushort* xbf  = (ushort*)alloc((size_t)N_NODES * IN_C * 2);   // planar [4][N][32]
    ushort* bufA = (ushort*)alloc((size_t)N_NODES * HID * 2);    // planar [8][N][32]
    ushort* bufB = (ushort*)alloc((size_t)N_NODES * HID * 2);    // row-major agg output
    ushort* wt[6];
    wt[0] = (ushort*)alloc((size_t)IN_C * HID * 2);
    for (int i = 1; i < 6; ++i) wt[i] = (ushort*)alloc((size_t)HID * HID * 2);
    float* sums   = (float*)alloc((size_t)N_GRAPHS * HID * 4);
    int* deg       = (int*)alloc((size_t)N_NODES * 4);
    int* rowptr    = (int*)alloc((size_t)(N_NODES + 1) * 4);
    int* blockSums = (int*)alloc(256 * 4);
    ushort* rank16 = (ushort*)alloc((size_t)N_EDGES * 2);
    uint* pack     = (uint*)alloc((size_t)N_EDGES * 4);
    ushort* srcSorted = (ushort*)alloc((size_t)N_EDGES * 2);     // USHORT indices

    const int nb = (N_NODES + 255) / 256;

    // ---- Prep: casts + zeroing ----
    {
        PrepArgs a;
        a.x = x;
        a.xbf = xbf;
        a.deg = deg;
        a.sums = sums;
        prep_kernel<<<2048, 256, 0, stream>>>(a);
    }
    // ---- Coalesced weight transposes (352 tiles of 32x32) ----
    {
        TransArgs ta;
        ta.w[0] = c_w1[0]; ta.w[1] = c_w2[0];
        ta.w[2] = c_w1[1]; ta.w[3] = c_w2[1];
        ta.w[4] = c_w1[2]; ta.w[5] = c_w2[2];
        for (int i = 0; i < 6; ++i) ta.wt[i] = wt[i];
        transpose_weights<<<352, 256, 0, stream>>>(ta);
    }

    // ---- Build CSR by dst: deg+rank+pack -> scan -> sharded scatter ----
    deg_rank_kernel<<<(N_EDGES + 255) / 256, 256, 0, stream>>>(src, dst, deg, rank16, pack);
    scan_block<<<nb, 256, 0, stream>>>(deg, rowptr, blockSums);
    add_offsets_fused<<<nb, 256, 0, stream>>>(rowptr, blockSums, rowptr, nb);
    {
        const int chunks = (N_EDGES + EDGES_PER_BLK - 1) / EDGES_PER_BLK;  // 391
        scatter_edges_sharded<<<chunks * NSHARD, 256, 0, stream>>>(pack, rank16, rowptr, srcSorted);
    }

    const int nodeBlks = (N_NODES + 63) / 64;        // 782 (even, needed for PER=2)
    const int aggX128  = nodeBlks * (IN_C / 32);     // 3128
    const int aggX256  = nodeBlks * (HID / 32);      // 6256
    const int NPERS    = 256;                        // persistent MLP grid (1/CU)

    // ---- Layer 0 (C_in = 128) ----
    gin_aggregate_planar<IN_C><<<aggX128, 256, 0, stream>>>(xbf, rowptr, srcSorted, bufB);
    gin_mlp_persist<IN_C, false><<<NPERS, 512, 0, stream>>>(bufB, wt[0], c_b1[0], wt[1], c_b2[0],
                                                            bufA, batch, sums, N_NODES, nodeBlks, NPERS);

    // ---- Layer 1 (C = 256) ----
    gin_aggregate_planar<HID><<<aggX256, 256, 0, stream>>>(bufA, rowptr, srcSorted, bufB);
    gin_mlp_persist<HID, false><<<NPERS, 512, 0, stream>>>(bufB, wt[2], c_b1[1], wt[3], c_b2[1],
                                                           bufA, batch, sums, N_NODES, nodeBlks, NPERS);

    // ---- Layer 2 (C = 256) with fused global mean-pool accumulation ----
    gin_aggregate_planar<HID><<<aggX256, 256, 0, stream>>>(bufA, rowptr, srcSorted, bufB);
    gin_mlp_persist<HID, true><<<NPERS, 512, 0, stream>>>(bufB, wt[4], c_b1[2], wt[5], c_b2[2],
                                                          bufA, batch, sums, N_NODES, nodeBlks, NPERS);

    // ---- Head MLP ----
    final_mlp_kernel<<<N_GRAPHS, 256, 0, stream>>>(sums, batch, out_w1, out_b1,
                                                   out_w2, out_b2, (float*)d_out);
}